// Round 7
// baseline (411.848 us; speedup 1.0000x reference)
//
#include <hip/hip_runtime.h>
#include <hip/hip_bf16.h>

#define LL 2048
#define CC 64

typedef __bf16 bf16x8 __attribute__((ext_vector_type(8)));
typedef float f32x4 __attribute__((ext_vector_type(4)));

// native RNE casts -> v_cvt_pk_bf16_f32 on gfx950
__device__ __forceinline__ bf16x8 mk8(f32x4 lo, f32x4 hi) {
  bf16x8 r;
  r[0] = (__bf16)lo[0]; r[1] = (__bf16)lo[1]; r[2] = (__bf16)lo[2]; r[3] = (__bf16)lo[3];
  r[4] = (__bf16)hi[0]; r[5] = (__bf16)hi[1]; r[6] = (__bf16)hi[2]; r[7] = (__bf16)hi[3];
  return r;
}

// async global->LDS, 16B per lane, NT cache policy (stream-once data)
__device__ __forceinline__ void gl16nt(const float* g, float* l) {
  __builtin_amdgcn_global_load_lds(
      (const __attribute__((address_space(1))) unsigned int*)g,
      (__attribute__((address_space(3))) unsigned int*)l, 16, 0, 2 /*NT*/);
}

#define SB0() __builtin_amdgcn_sched_barrier(0)

// ws map (floats): [0,512) accum | [512,2560) dt (dt[2047]=0) |
//                  [2560, 2560+131072) negated Y2 frags | [133632,134144) int counters
__global__ void prep_k(const float* __restrict__ times, const float* __restrict__ path2,
                       const float* __restrict__ Amat, float* __restrict__ ws) {
  const int tid = threadIdx.x;
  const int gtid = blockIdx.x * 256 + tid;     // 32 blocks * 256 = 8192
  if (gtid < 512) {
    ws[gtid] = 0.f;
    ((int*)(ws + 133632))[gtid] = 0;
  }
  float* dt = ws + 512;
  if (gtid < 2048) dt[gtid] = (gtid < 2047) ? times[gtid + 1] - times[gtid] : 0.f;

  const int lane = tid & 63;
  const int wv = gtid >> 6;                    // 0..127 : tile index
  const int c = lane & 15, g = lane >> 4;

  bf16x8 bfr[4][2];
  #pragma unroll
  for (int t = 0; t < 4; ++t) {
    #pragma unroll
    for (int s = 0; s < 2; ++s) {
      const float* ap = Amat + (16 * t + c) * CC + 32 * s + (g << 3);
      f32x4 x0 = *(const f32x4*)ap;
      f32x4 x1 = *(const f32x4*)(ap + 4);
      bfr[t][s] = mk8(x0, x1);
    }
  }

  const int row = (wv << 4) + c;
  const float* pp2 = path2 + (size_t)row * CC + (g << 3);
  f32x4 b0 = *(const f32x4*)(pp2);      f32x4 b1 = *(const f32x4*)(pp2 + 4);
  f32x4 b2 = *(const f32x4*)(pp2 + 32); f32x4 b3 = *(const f32x4*)(pp2 + 36);
  bf16x8 af0 = mk8(b0, b1);
  bf16x8 af1 = mk8(b2, b3);

  f32x4 y[4];
  #pragma unroll
  for (int t = 0; t < 4; ++t) { f32x4 zz = {0.f,0.f,0.f,0.f}; y[t] = zz; }
  #pragma unroll
  for (int t = 0; t < 4; ++t)
    y[t] = __builtin_amdgcn_mfma_f32_16x16x32_bf16(af0, bfr[t][0], y[t], 0, 0, 0);
  #pragma unroll
  for (int t = 0; t < 4; ++t)
    y[t] = __builtin_amdgcn_mfma_f32_16x16x32_bf16(af1, bfr[t][1], y[t], 0, 0, 0);

  float* Y2 = ws + 2560;
  #pragma unroll
  for (int t = 0; t < 4; ++t)
    *(f32x4*)(Y2 + wv * 1024 + t * 256 + (lane << 2)) = -y[t];   // store NEGATED
}

__global__ __launch_bounds__(256, 3) void l2disc_main(
    const float* __restrict__ path1, const float* __restrict__ Amat,
    float* __restrict__ ws, float* __restrict__ out)
{
  // 4 waves * 3 buffers * 1024 floats = 48 KB
  __shared__ float lds[12288];

  const int lane = threadIdx.x & 63;
  const int wave = threadIdx.x >> 6;
  const int c = lane & 15;
  const int g = lane >> 4;
  const int b = blockIdx.x >> 2;
  const int q = ((blockIdx.x & 3) << 2) | wave;   // span 0..15
  const int p0 = q << 7;

  const float* dt = ws + 512;
  const float* Y2 = ws + 2560;

  bf16x8 bfr[4][2];
  #pragma unroll
  for (int t = 0; t < 4; ++t) {
    #pragma unroll
    for (int s = 0; s < 2; ++s) {
      const float* ap = Amat + (16 * t + c) * CC + 32 * s + (g << 3);
      f32x4 x0 = *(const f32x4*)ap;
      f32x4 x1 = *(const f32x4*)(ap + 4);
      bfr[t][s] = mk8(x0, x1);
    }
  }

  // swizzled STAGE source offsets: row = 4j + (l>>4), f' = f ^ ((row&7)<<2)
  const int lr = lane >> 4, lcf = (lane & 15) << 2;
  const int soffE = lr * 64 + (lcf ^ (lr << 2));         // j even
  const int soffO = lr * 64 + (lcf ^ ((lr + 4) << 2));   // j odd
  // swizzled READ offsets within a 1024-float tile
  const int swz = (c & 7) << 2;
  const int rf0 = c * 64 + ((g << 3) ^ swz);
  const int rf1 = c * 64 + (((g << 3) | 4) ^ swz);

  float* const wl = lds + wave * 3072;
  float* const B0 = wl, * const B1 = wl + 1024, * const B2 = wl + 2048;
  const float* p1base = path1 + (size_t)b * LL * CC;

  float wacc = 0.f;
  f32x4 prev = {0.f, 0.f, 0.f, 0.f};
  float dm1carry = 0.f;

  auto PREY = [&](int i, f32x4* y2v, f32x4& dt4) {          // 5 VMEM ops
    const int tidx = min((q << 3) + i, 127);
    const float* yb = Y2 + tidx * 1024 + (lane << 2);
    #pragma unroll
    for (int t = 0; t < 4; ++t) y2v[t] = *(const f32x4*)(yb + t * 256);
    const int rd = min(p0 + (i << 4) + (g << 2), LL - 4);
    dt4 = *(const f32x4*)(dt + rd);
  };

  auto PREG = [&](int i, float* dbuf) {                     // 4 VMEM ops
    const int r0 = p0 + (i << 4);
    const float* s1 = p1base + (size_t)r0 * CC;
    gl16nt(s1 +       soffE, dbuf);
    gl16nt(s1 + 256 + soffO, dbuf + 256);
    gl16nt(s1 + 512 + soffE, dbuf + 512);
    gl16nt(s1 + 768 + soffO, dbuf + 768);
  };

  auto PREG8 = [&](float* dbuf) {                           // 1 VMEM op
    const int r0 = (q == 15) ? (LL - 16) : (p0 + 128);      // fake tile for q==15
    gl16nt(p1base + (size_t)r0 * CC + soffE, dbuf);         // rows r0..r0+3
  };

  auto COMP = [&](const float* u1, const f32x4* y2v, f32x4 dt4, bool full, bool first) {
    f32x4 a0 = *(const f32x4*)(u1 + rf0);
    f32x4 a1 = *(const f32x4*)(u1 + rf1);
    f32x4 a2 = *(const f32x4*)(u1 + rf0 + 32);
    f32x4 a3 = *(const f32x4*)(u1 + rf1 + 32);

    bf16x8 af0 = mk8(a0, a1);
    bf16x8 af1 = mk8(a2, a3);

    f32x4 y[4];
    #pragma unroll
    for (int t = 0; t < 4; ++t) y[t] = y2v[t];              // acc init = -A*p2
    #pragma unroll
    for (int t = 0; t < 4; ++t)
      y[t] = __builtin_amdgcn_mfma_f32_16x16x32_bf16(af0, bfr[t][0], y[t], 0, 0, 0);
    #pragma unroll
    for (int t = 0; t < 4; ++t)
      y[t] = __builtin_amdgcn_mfma_f32_16x16x32_bf16(af1, bfr[t][1], y[t], 0, 0, 0);

    const float d0 = dt4[0], d1 = dt4[1], d2 = dt4[2], d3 = dt4[3];
    const float dm1 = dm1carry;

    if (full) {
      float s0 = 0.f, s1 = 0.f, s2 = 0.f;
      #pragma unroll
      for (int t = 0; t < 4; ++t) {
        float a, bb;
        a = y[t][0]; bb = y[t][1]; s0 += a*a + a*bb + bb*bb;
        a = y[t][1]; bb = y[t][2]; s1 += a*a + a*bb + bb*bb;
        a = y[t][2]; bb = y[t][3]; s2 += a*a + a*bb + bb*bb;
      }
      wacc += d0 * s0 + d1 * s1 + d2 * s2;
      float nb0 = __shfl_down(y[0][0], 16);
      float nb1 = __shfl_down(y[1][0], 16);
      float nb2 = __shfl_down(y[2][0], 16);
      float nb3 = __shfl_down(y[3][0], 16);
      if (g < 3) {
        float a, s = 0.f;
        a = y[0][3]; s += a*a + a*nb0 + nb0*nb0;
        a = y[1][3]; s += a*a + a*nb1 + nb1*nb1;
        a = y[2][3]; s += a*a + a*nb2 + nb2*nb2;
        a = y[3][3]; s += a*a + a*nb3 + nb3*nb3;
        wacc += d3 * s;
      }
    }
    if (!first && g == 0) {
      float s = 0.f;
      #pragma unroll
      for (int t = 0; t < 4; ++t) {
        float a = prev[t], bb = y[t][0];
        s += a*a + a*bb + bb*bb;
      }
      wacc += dm1 * s;     // q==15 fake tile: dm1 = dt[2047] = 0
    }
    if (full) {
      #pragma unroll
      for (int t = 0; t < 4; ++t) prev[t] = __shfl(y[t][3], 48 + c);
    }
    dm1carry = __shfl(d3, 48);
  };

  f32x4 y2A[4], y2B[4], dt4A, dt4B;

#define GATE(N) SB0(); asm volatile("s_waitcnt vmcnt(" #N ")" ::: "memory"); SB0()

  // prologue: Y(0) then G(0), G(1)
  PREY(0, y2A, dt4A); SB0();
  PREG(0, B0); PREG(1, B1);
  // iter 0
  PREY(1, y2B, dt4B); SB0(); PREG(2, B2); GATE(13); COMP(B0, y2A, dt4A, true, true);
  // iter 1
  PREY(2, y2A, dt4A); SB0(); PREG(3, B0); GATE(13); COMP(B1, y2B, dt4B, true, false);
  // iter 2
  PREY(3, y2B, dt4B); SB0(); PREG(4, B1); GATE(13); COMP(B2, y2A, dt4A, true, false);
  // iter 3
  PREY(4, y2A, dt4A); SB0(); PREG(5, B2); GATE(13); COMP(B0, y2B, dt4B, true, false);
  // iter 4
  PREY(5, y2B, dt4B); SB0(); PREG(6, B0); GATE(13); COMP(B1, y2A, dt4A, true, false);
  // iter 5
  PREY(6, y2A, dt4A); SB0(); PREG(7, B1); GATE(13); COMP(B2, y2B, dt4B, true, false);
  // iter 6
  PREY(7, y2B, dt4B); SB0(); PREG8(B2);   GATE(10); COMP(B0, y2A, dt4A, true, false);
  // iter 7
  PREY(8, y2A, dt4A); SB0();              GATE(6);  COMP(B1, y2B, dt4B, true, false);
  // iter 8 (overlap tile: only cross-tile pair counts)
                                          GATE(0);  COMP(B2, y2A, dt4A, false, false);
#undef GATE

  // ---- wave reduce + one atomic per wave; last wave of batch finalizes out[b]
  #pragma unroll
  for (int off = 32; off > 0; off >>= 1) wacc += __shfl_down(wacc, off);
  if (lane == 0) {
    atomicAdd(ws + b, wacc);
    __threadfence();
    int* cnt = (int*)(ws + 133632);
    int old = atomicAdd(cnt + b, 1);
    if (old == 15) {                       // 16 waves per batch -> last one
      float v = atomicAdd(ws + b, 0.f);    // atomic read, device-coherent
      out[b] = sqrtf(v * (1.0f / 3.0f));
    }
  }
}

extern "C" void kernel_launch(void* const* d_in, const int* in_sizes, int n_in,
                              void* d_out, int out_size, void* d_ws, size_t ws_size,
                              hipStream_t stream) {
  const float* times = (const float*)d_in[0];
  const float* path1 = (const float*)d_in[1];
  const float* path2 = (const float*)d_in[2];
  const float* Amat  = (const float*)d_in[3];
  float* out = (float*)d_out;
  float* ws  = (float*)d_ws;
  const int B = in_sizes[1] / (LL * CC);  // 512

  hipLaunchKernelGGL(prep_k, dim3(32), dim3(256), 0, stream, times, path2, Amat, ws);
  hipLaunchKernelGGL(l2disc_main, dim3(B * 4), dim3(256), 0, stream, path1, Amat, ws, out);
}

// Round 8
// 67.096 us; speedup vs baseline: 6.1382x; 6.1382x over previous
//
#include <hip/hip_runtime.h>
#include <hip/hip_bf16.h>

#define LL 2048
#define CC 64

typedef __bf16 bf16x8 __attribute__((ext_vector_type(8)));
typedef float f32x4 __attribute__((ext_vector_type(4)));

// native RNE casts -> v_cvt_pk_bf16_f32 on gfx950
__device__ __forceinline__ bf16x8 mk8(f32x4 lo, f32x4 hi) {
  bf16x8 r;
  r[0] = (__bf16)lo[0]; r[1] = (__bf16)lo[1]; r[2] = (__bf16)lo[2]; r[3] = (__bf16)lo[3];
  r[4] = (__bf16)hi[0]; r[5] = (__bf16)hi[1]; r[6] = (__bf16)hi[2]; r[7] = (__bf16)hi[3];
  return r;
}

// async global->LDS, 16B per lane (aux=0: default cache policy)
__device__ __forceinline__ void gl16(const float* g, float* l) {
  __builtin_amdgcn_global_load_lds(
      (const __attribute__((address_space(1))) unsigned int*)g,
      (__attribute__((address_space(3))) unsigned int*)l, 16, 0, 0);
}

#define SB0() __builtin_amdgcn_sched_barrier(0)

// ws map (floats): [0,512) accum | [512,2560) dt (dt[2047]=0) |
//                  [2560, 133632) negated Y2 frags | [133632,134144) int counters
__global__ void prep_k(const float* __restrict__ times, const float* __restrict__ path2,
                       const float* __restrict__ Amat, float* __restrict__ ws) {
  const int tid = threadIdx.x;
  const int gtid = blockIdx.x * 256 + tid;     // 32 blocks * 256 = 8192
  if (gtid < 512) {
    ws[gtid] = 0.f;
    ((int*)(ws + 133632))[gtid] = 0;
  }
  float* dt = ws + 512;
  if (gtid < 2048) dt[gtid] = (gtid < 2047) ? times[gtid + 1] - times[gtid] : 0.f;

  const int lane = tid & 63;
  const int wv = gtid >> 6;                    // 0..127 : tile index
  const int c = lane & 15, g = lane >> 4;

  bf16x8 bfr[4][2];
  #pragma unroll
  for (int t = 0; t < 4; ++t) {
    #pragma unroll
    for (int s = 0; s < 2; ++s) {
      const float* ap = Amat + (16 * t + c) * CC + 32 * s + (g << 3);
      f32x4 x0 = *(const f32x4*)ap;
      f32x4 x1 = *(const f32x4*)(ap + 4);
      bfr[t][s] = mk8(x0, x1);
    }
  }

  const int row = (wv << 4) + c;
  const float* pp2 = path2 + (size_t)row * CC + (g << 3);
  f32x4 b0 = *(const f32x4*)(pp2);      f32x4 b1 = *(const f32x4*)(pp2 + 4);
  f32x4 b2 = *(const f32x4*)(pp2 + 32); f32x4 b3 = *(const f32x4*)(pp2 + 36);
  bf16x8 af0 = mk8(b0, b1);
  bf16x8 af1 = mk8(b2, b3);

  f32x4 y[4];
  #pragma unroll
  for (int t = 0; t < 4; ++t) { f32x4 zz = {0.f,0.f,0.f,0.f}; y[t] = zz; }
  #pragma unroll
  for (int t = 0; t < 4; ++t)
    y[t] = __builtin_amdgcn_mfma_f32_16x16x32_bf16(af0, bfr[t][0], y[t], 0, 0, 0);
  #pragma unroll
  for (int t = 0; t < 4; ++t)
    y[t] = __builtin_amdgcn_mfma_f32_16x16x32_bf16(af1, bfr[t][1], y[t], 0, 0, 0);

  float* Y2 = ws + 2560;
  #pragma unroll
  for (int t = 0; t < 4; ++t)
    *(f32x4*)(Y2 + wv * 1024 + t * 256 + (lane << 2)) = -y[t];   // store NEGATED
}

__global__ __launch_bounds__(256, 3) void l2disc_main(
    const float* __restrict__ path1, const float* __restrict__ Amat,
    float* __restrict__ ws, float* __restrict__ out)
{
  // 4 waves * 3 buffers * 1024 floats = 48 KB
  __shared__ float lds[12288];

  const int lane = threadIdx.x & 63;
  const int wave = threadIdx.x >> 6;
  const int c = lane & 15;
  const int g = lane >> 4;
  const int b = blockIdx.x >> 2;
  const int q = ((blockIdx.x & 3) << 2) | wave;   // span 0..15
  const int p0 = q << 7;

  const float* dt = ws + 512;
  const float* Y2 = ws + 2560;

  bf16x8 bfr[4][2];
  #pragma unroll
  for (int t = 0; t < 4; ++t) {
    #pragma unroll
    for (int s = 0; s < 2; ++s) {
      const float* ap = Amat + (16 * t + c) * CC + 32 * s + (g << 3);
      f32x4 x0 = *(const f32x4*)ap;
      f32x4 x1 = *(const f32x4*)(ap + 4);
      bfr[t][s] = mk8(x0, x1);
    }
  }

  // swizzled STAGE source offsets: row = 4j + (l>>4), f' = f ^ ((row&7)<<2)
  const int lr = lane >> 4, lcf = (lane & 15) << 2;
  const int soffE = lr * 64 + (lcf ^ (lr << 2));         // j even
  const int soffO = lr * 64 + (lcf ^ ((lr + 4) << 2));   // j odd
  // swizzled READ offsets within a 1024-float tile
  const int swz = (c & 7) << 2;
  const int rf0 = c * 64 + ((g << 3) ^ swz);
  const int rf1 = c * 64 + (((g << 3) | 4) ^ swz);

  float* const wl = lds + wave * 3072;
  float* const B0 = wl, * const B1 = wl + 1024, * const B2 = wl + 2048;
  const float* p1base = path1 + (size_t)b * LL * CC;

  float wacc = 0.f;
  f32x4 prev = {0.f, 0.f, 0.f, 0.f};
  float dm1carry = 0.f;

  auto PREY = [&](int i, f32x4* y2v, f32x4& dt4) {          // 5 VMEM ops
    const int tidx = min((q << 3) + i, 127);
    const float* yb = Y2 + tidx * 1024 + (lane << 2);
    #pragma unroll
    for (int t = 0; t < 4; ++t) y2v[t] = *(const f32x4*)(yb + t * 256);
    const int rd = min(p0 + (i << 4) + (g << 2), LL - 4);
    dt4 = *(const f32x4*)(dt + rd);
  };

  auto PREG = [&](int i, float* dbuf) {                     // 4 VMEM ops
    const int r0 = p0 + (i << 4);
    const float* s1 = p1base + (size_t)r0 * CC;
    gl16(s1 +       soffE, dbuf);
    gl16(s1 + 256 + soffO, dbuf + 256);
    gl16(s1 + 512 + soffE, dbuf + 512);
    gl16(s1 + 768 + soffO, dbuf + 768);
  };

  auto PREG8 = [&](float* dbuf) {                           // 1 VMEM op
    const int r0 = (q == 15) ? (LL - 16) : (p0 + 128);      // fake tile for q==15
    gl16(p1base + (size_t)r0 * CC + soffE, dbuf);           // rows r0..r0+3
  };

  auto COMP = [&](const float* u1, const f32x4* y2v, f32x4 dt4, bool full, bool first) {
    f32x4 a0 = *(const f32x4*)(u1 + rf0);
    f32x4 a1 = *(const f32x4*)(u1 + rf1);
    f32x4 a2 = *(const f32x4*)(u1 + rf0 + 32);
    f32x4 a3 = *(const f32x4*)(u1 + rf1 + 32);

    bf16x8 af0 = mk8(a0, a1);
    bf16x8 af1 = mk8(a2, a3);

    f32x4 y[4];
    #pragma unroll
    for (int t = 0; t < 4; ++t) y[t] = y2v[t];              // acc init = -A*p2
    #pragma unroll
    for (int t = 0; t < 4; ++t)
      y[t] = __builtin_amdgcn_mfma_f32_16x16x32_bf16(af0, bfr[t][0], y[t], 0, 0, 0);
    #pragma unroll
    for (int t = 0; t < 4; ++t)
      y[t] = __builtin_amdgcn_mfma_f32_16x16x32_bf16(af1, bfr[t][1], y[t], 0, 0, 0);

    const float d0 = dt4[0], d1 = dt4[1], d2 = dt4[2], d3 = dt4[3];
    const float dm1 = dm1carry;

    if (full) {
      float s0 = 0.f, s1 = 0.f, s2 = 0.f;
      #pragma unroll
      for (int t = 0; t < 4; ++t) {
        float a, bb;
        a = y[t][0]; bb = y[t][1]; s0 += a*a + a*bb + bb*bb;
        a = y[t][1]; bb = y[t][2]; s1 += a*a + a*bb + bb*bb;
        a = y[t][2]; bb = y[t][3]; s2 += a*a + a*bb + bb*bb;
      }
      wacc += d0 * s0 + d1 * s1 + d2 * s2;
      float nb0 = __shfl_down(y[0][0], 16);
      float nb1 = __shfl_down(y[1][0], 16);
      float nb2 = __shfl_down(y[2][0], 16);
      float nb3 = __shfl_down(y[3][0], 16);
      if (g < 3) {
        float a, s = 0.f;
        a = y[0][3]; s += a*a + a*nb0 + nb0*nb0;
        a = y[1][3]; s += a*a + a*nb1 + nb1*nb1;
        a = y[2][3]; s += a*a + a*nb2 + nb2*nb2;
        a = y[3][3]; s += a*a + a*nb3 + nb3*nb3;
        wacc += d3 * s;
      }
    }
    if (!first && g == 0) {
      float s = 0.f;
      #pragma unroll
      for (int t = 0; t < 4; ++t) {
        float a = prev[t], bb = y[t][0];
        s += a*a + a*bb + bb*bb;
      }
      wacc += dm1 * s;     // q==15 fake tile: dm1 = dt[2047] = 0
    }
    if (full) {
      #pragma unroll
      for (int t = 0; t < 4; ++t) prev[t] = __shfl(y[t][3], 48 + c);
    }
    dm1carry = __shfl(d3, 48);
  };

  f32x4 y2A[4], y2B[4], dt4A, dt4B;

#define GATE(N) SB0(); asm volatile("s_waitcnt vmcnt(" #N ")" ::: "memory"); SB0()

  // prologue: Y(0) then G(0), G(1)
  PREY(0, y2A, dt4A); SB0();
  PREG(0, B0); PREG(1, B1);
  // iter 0
  PREY(1, y2B, dt4B); SB0(); PREG(2, B2); GATE(13); COMP(B0, y2A, dt4A, true, true);
  // iter 1
  PREY(2, y2A, dt4A); SB0(); PREG(3, B0); GATE(13); COMP(B1, y2B, dt4B, true, false);
  // iter 2
  PREY(3, y2B, dt4B); SB0(); PREG(4, B1); GATE(13); COMP(B2, y2A, dt4A, true, false);
  // iter 3
  PREY(4, y2A, dt4A); SB0(); PREG(5, B2); GATE(13); COMP(B0, y2B, dt4B, true, false);
  // iter 4
  PREY(5, y2B, dt4B); SB0(); PREG(6, B0); GATE(13); COMP(B1, y2A, dt4A, true, false);
  // iter 5
  PREY(6, y2A, dt4A); SB0(); PREG(7, B1); GATE(13); COMP(B2, y2B, dt4B, true, false);
  // iter 6
  PREY(7, y2B, dt4B); SB0(); PREG8(B2);   GATE(10); COMP(B0, y2A, dt4A, true, false);
  // iter 7
  PREY(8, y2A, dt4A); SB0();              GATE(6);  COMP(B1, y2B, dt4B, true, false);
  // iter 8 (overlap tile: only cross-tile pair counts)
                                          GATE(0);  COMP(B2, y2A, dt4A, false, false);
#undef GATE

  // ---- wave reduce; fence-free fused finalize via same-address atomic ordering
  #pragma unroll
  for (int off = 32; off > 0; off >>= 1) wacc += __shfl_down(wacc, off);
  if (lane == 0) {
    float oldv = atomicAdd(ws + b, wacc);          // returning form: ack at coherence point
    asm volatile("" :: "v"(oldv));                 // keep the return value live
    asm volatile("s_waitcnt vmcnt(0)" ::: "memory"); // ws-add globally performed before cnt-add
    int* cnt = (int*)(ws + 133632);
    int old = atomicAdd(cnt + b, 1);
    if (old == 15) {                               // 16th (last) wave of this batch
      float v = atomicAdd(ws + b, 0.f);            // atomic read: sees all 16 adds
      out[b] = sqrtf(v * (1.0f / 3.0f));
    }
  }
}

extern "C" void kernel_launch(void* const* d_in, const int* in_sizes, int n_in,
                              void* d_out, int out_size, void* d_ws, size_t ws_size,
                              hipStream_t stream) {
  const float* times = (const float*)d_in[0];
  const float* path1 = (const float*)d_in[1];
  const float* path2 = (const float*)d_in[2];
  const float* Amat  = (const float*)d_in[3];
  float* out = (float*)d_out;
  float* ws  = (float*)d_ws;
  const int B = in_sizes[1] / (LL * CC);  // 512

  hipLaunchKernelGGL(prep_k, dim3(32), dim3(256), 0, stream, times, path2, Amat, ws);
  hipLaunchKernelGGL(l2disc_main, dim3(B * 4), dim3(256), 0, stream, path1, Amat, ws, out);
}

// Round 9
// 65.789 us; speedup vs baseline: 6.2601x; 1.0199x over previous
//
#include <hip/hip_runtime.h>
#include <hip/hip_bf16.h>

#define LL 2048
#define CC 64

typedef __bf16 bf16x8 __attribute__((ext_vector_type(8)));
typedef float f32x4 __attribute__((ext_vector_type(4)));
typedef unsigned int u32x4 __attribute__((ext_vector_type(4)));

// native RNE casts -> v_cvt_pk_bf16_f32 on gfx950
__device__ __forceinline__ bf16x8 mk8(f32x4 lo, f32x4 hi) {
  bf16x8 r;
  r[0] = (__bf16)lo[0]; r[1] = (__bf16)lo[1]; r[2] = (__bf16)lo[2]; r[3] = (__bf16)lo[3];
  r[4] = (__bf16)hi[0]; r[5] = (__bf16)hi[1]; r[6] = (__bf16)hi[2]; r[7] = (__bf16)hi[3];
  return r;
}

// pack two floats as bf16 pair: [15:0]=bf(a), [31:16]=bf(b)
__device__ __forceinline__ unsigned pk2(float a, float b) {
  __bf16 x = (__bf16)a, y = (__bf16)b;
  unsigned short ux = __builtin_bit_cast(unsigned short, x);
  unsigned short uy = __builtin_bit_cast(unsigned short, y);
  return (unsigned)ux | ((unsigned)uy << 16);
}

// unpack bf16 pair -> two exact f32 (bits<<16)
__device__ __forceinline__ f32x4 mky(unsigned ua, unsigned ub) {
  f32x4 r;
  r[0] = __builtin_bit_cast(float, ua << 16);
  r[1] = __builtin_bit_cast(float, ua & 0xffff0000u);
  r[2] = __builtin_bit_cast(float, ub << 16);
  r[3] = __builtin_bit_cast(float, ub & 0xffff0000u);
  return r;
}

// async global->LDS, 16B per lane (default cache policy)
__device__ __forceinline__ void gl16(const float* g, float* l) {
  __builtin_amdgcn_global_load_lds(
      (const __attribute__((address_space(1))) unsigned int*)g,
      (__attribute__((address_space(3))) unsigned int*)l, 16, 0, 0);
}

#define SB0() __builtin_amdgcn_sched_barrier(0)

// ws map (floats): [0,512) accum | [512,2560) dt (dt[2047]=0) |
//   [2560, 2560+65536) packed bf16 -Y2 (u32 units: tile*512 + lane*8 + t*2 + w) |
//   [133632,134144) int counters
__global__ void prep_k(const float* __restrict__ times, const float* __restrict__ path2,
                       const float* __restrict__ Amat, float* __restrict__ ws) {
  const int tid = threadIdx.x;
  const int gtid = blockIdx.x * 256 + tid;     // 32 blocks * 256 = 8192
  if (gtid < 512) {
    ws[gtid] = 0.f;
    ((int*)(ws + 133632))[gtid] = 0;
  }
  float* dt = ws + 512;
  if (gtid < 2048) dt[gtid] = (gtid < 2047) ? times[gtid + 1] - times[gtid] : 0.f;

  const int lane = tid & 63;
  const int wv = gtid >> 6;                    // 0..127 : tile index
  const int c = lane & 15, g = lane >> 4;

  bf16x8 bfr[4][2];
  #pragma unroll
  for (int t = 0; t < 4; ++t) {
    #pragma unroll
    for (int s = 0; s < 2; ++s) {
      const float* ap = Amat + (16 * t + c) * CC + 32 * s + (g << 3);
      f32x4 x0 = *(const f32x4*)ap;
      f32x4 x1 = *(const f32x4*)(ap + 4);
      bfr[t][s] = mk8(x0, x1);
    }
  }

  const int row = (wv << 4) + c;
  const float* pp2 = path2 + (size_t)row * CC + (g << 3);
  f32x4 b0 = *(const f32x4*)(pp2);      f32x4 b1 = *(const f32x4*)(pp2 + 4);
  f32x4 b2 = *(const f32x4*)(pp2 + 32); f32x4 b3 = *(const f32x4*)(pp2 + 36);
  bf16x8 af0 = mk8(b0, b1);
  bf16x8 af1 = mk8(b2, b3);

  f32x4 y[4];
  #pragma unroll
  for (int t = 0; t < 4; ++t) { f32x4 zz = {0.f,0.f,0.f,0.f}; y[t] = zz; }
  #pragma unroll
  for (int t = 0; t < 4; ++t)
    y[t] = __builtin_amdgcn_mfma_f32_16x16x32_bf16(af0, bfr[t][0], y[t], 0, 0, 0);
  #pragma unroll
  for (int t = 0; t < 4; ++t)
    y[t] = __builtin_amdgcn_mfma_f32_16x16x32_bf16(af1, bfr[t][1], y[t], 0, 0, 0);

  // store NEGATED Y2, packed bf16, per-lane contiguous 32 B
  unsigned* Y2b = (unsigned*)(ws + 2560);
  u32x4 lo = { pk2(-y[0][0], -y[0][1]), pk2(-y[0][2], -y[0][3]),
               pk2(-y[1][0], -y[1][1]), pk2(-y[1][2], -y[1][3]) };
  u32x4 hi = { pk2(-y[2][0], -y[2][1]), pk2(-y[2][2], -y[2][3]),
               pk2(-y[3][0], -y[3][1]), pk2(-y[3][2], -y[3][3]) };
  *(u32x4*)(Y2b + wv * 512 + lane * 8)     = lo;
  *(u32x4*)(Y2b + wv * 512 + lane * 8 + 4) = hi;
}

__global__ __launch_bounds__(256, 3) void l2disc_main(
    const float* __restrict__ path1, const float* __restrict__ Amat,
    float* __restrict__ ws, float* __restrict__ out)
{
  // 4 waves * 3 buffers * 1024 floats = 48 KB
  __shared__ float lds[12288];

  const int lane = threadIdx.x & 63;
  const int wave = threadIdx.x >> 6;
  const int c = lane & 15;
  const int g = lane >> 4;
  const int b = blockIdx.x >> 2;
  const int q = ((blockIdx.x & 3) << 2) | wave;   // span 0..15
  const int p0 = q << 7;

  const float* dt = ws + 512;
  const unsigned* Y2b = (const unsigned*)(ws + 2560);

  bf16x8 bfr[4][2];
  #pragma unroll
  for (int t = 0; t < 4; ++t) {
    #pragma unroll
    for (int s = 0; s < 2; ++s) {
      const float* ap = Amat + (16 * t + c) * CC + 32 * s + (g << 3);
      f32x4 x0 = *(const f32x4*)ap;
      f32x4 x1 = *(const f32x4*)(ap + 4);
      bfr[t][s] = mk8(x0, x1);
    }
  }

  // swizzled STAGE source offsets: row = 4j + (l>>4), f' = f ^ ((row&7)<<2)
  const int lr = lane >> 4, lcf = (lane & 15) << 2;
  const int soffE = lr * 64 + (lcf ^ (lr << 2));         // j even
  const int soffO = lr * 64 + (lcf ^ ((lr + 4) << 2));   // j odd
  // swizzled READ offsets within a 1024-float tile
  const int swz = (c & 7) << 2;
  const int rf0 = c * 64 + ((g << 3) ^ swz);
  const int rf1 = c * 64 + (((g << 3) | 4) ^ swz);

  float* const wl = lds + wave * 3072;
  float* const B0 = wl, * const B1 = wl + 1024, * const B2 = wl + 2048;
  const float* p1base = path1 + (size_t)b * LL * CC;

  float wacc = 0.f;
  f32x4 prev = {0.f, 0.f, 0.f, 0.f};
  float dm1carry = 0.f;

  auto PREY = [&](int i, u32x4& pa, u32x4& pb, f32x4& dt4) { // 3 VMEM ops
    const int tidx = min((q << 3) + i, 127);
    const unsigned* yb = Y2b + tidx * 512 + lane * 8;
    pa = *(const u32x4*)(yb);
    pb = *(const u32x4*)(yb + 4);
    const int rd = min(p0 + (i << 4) + (g << 2), LL - 4);
    dt4 = *(const f32x4*)(dt + rd);
  };

  auto PREG = [&](int i, float* dbuf) {                     // 4 VMEM ops
    const int r0 = p0 + (i << 4);
    const float* s1 = p1base + (size_t)r0 * CC;
    gl16(s1 +       soffE, dbuf);
    gl16(s1 + 256 + soffO, dbuf + 256);
    gl16(s1 + 512 + soffE, dbuf + 512);
    gl16(s1 + 768 + soffO, dbuf + 768);
  };

  auto PREG8 = [&](float* dbuf) {                           // 1 VMEM op
    const int r0 = (q == 15) ? (LL - 16) : (p0 + 128);      // fake tile for q==15
    gl16(p1base + (size_t)r0 * CC + soffE, dbuf);           // rows r0..r0+3
  };

  auto COMP = [&](const float* u1, u32x4 pa, u32x4 pb, f32x4 dt4, bool full, bool first) {
    f32x4 a0 = *(const f32x4*)(u1 + rf0);
    f32x4 a1 = *(const f32x4*)(u1 + rf1);
    f32x4 a2 = *(const f32x4*)(u1 + rf0 + 32);
    f32x4 a3 = *(const f32x4*)(u1 + rf1 + 32);

    bf16x8 af0 = mk8(a0, a1);
    bf16x8 af1 = mk8(a2, a3);

    f32x4 y[4];
    y[0] = mky(pa[0], pa[1]);                               // acc init = -A*p2
    y[1] = mky(pa[2], pa[3]);
    y[2] = mky(pb[0], pb[1]);
    y[3] = mky(pb[2], pb[3]);
    #pragma unroll
    for (int t = 0; t < 4; ++t)
      y[t] = __builtin_amdgcn_mfma_f32_16x16x32_bf16(af0, bfr[t][0], y[t], 0, 0, 0);
    #pragma unroll
    for (int t = 0; t < 4; ++t)
      y[t] = __builtin_amdgcn_mfma_f32_16x16x32_bf16(af1, bfr[t][1], y[t], 0, 0, 0);

    const float d0 = dt4[0], d1 = dt4[1], d2 = dt4[2], d3 = dt4[3];
    const float dm1 = dm1carry;

    if (full) {
      float s0 = 0.f, s1 = 0.f, s2 = 0.f;
      #pragma unroll
      for (int t = 0; t < 4; ++t) {
        float a, bb;
        a = y[t][0]; bb = y[t][1]; s0 += a*a + a*bb + bb*bb;
        a = y[t][1]; bb = y[t][2]; s1 += a*a + a*bb + bb*bb;
        a = y[t][2]; bb = y[t][3]; s2 += a*a + a*bb + bb*bb;
      }
      wacc += d0 * s0 + d1 * s1 + d2 * s2;
      float nb0 = __shfl_down(y[0][0], 16);
      float nb1 = __shfl_down(y[1][0], 16);
      float nb2 = __shfl_down(y[2][0], 16);
      float nb3 = __shfl_down(y[3][0], 16);
      if (g < 3) {
        float a, s = 0.f;
        a = y[0][3]; s += a*a + a*nb0 + nb0*nb0;
        a = y[1][3]; s += a*a + a*nb1 + nb1*nb1;
        a = y[2][3]; s += a*a + a*nb2 + nb2*nb2;
        a = y[3][3]; s += a*a + a*nb3 + nb3*nb3;
        wacc += d3 * s;
      }
    }
    if (!first && g == 0) {
      float s = 0.f;
      #pragma unroll
      for (int t = 0; t < 4; ++t) {
        float a = prev[t], bb = y[t][0];
        s += a*a + a*bb + bb*bb;
      }
      wacc += dm1 * s;     // q==15 fake tile: dm1 = dt[2047] = 0
    }
    if (full) {
      #pragma unroll
      for (int t = 0; t < 4; ++t) prev[t] = __shfl(y[t][3], 48 + c);
    }
    dm1carry = __shfl(d3, 48);
  };

  u32x4 yaA, ybA, yaB, ybB;
  f32x4 dt4A, dt4B;

#define GATE(N) SB0(); asm volatile("s_waitcnt vmcnt(" #N ")" ::: "memory"); SB0()

  // prologue: Y(0) then G(0), G(1)
  PREY(0, yaA, ybA, dt4A); SB0();
  PREG(0, B0); PREG(1, B1);
  // iter 0
  PREY(1, yaB, ybB, dt4B); SB0(); PREG(2, B2); GATE(11); COMP(B0, yaA, ybA, dt4A, true, true);
  // iter 1
  PREY(2, yaA, ybA, dt4A); SB0(); PREG(3, B0); GATE(11); COMP(B1, yaB, ybB, dt4B, true, false);
  // iter 2
  PREY(3, yaB, ybB, dt4B); SB0(); PREG(4, B1); GATE(11); COMP(B2, yaA, ybA, dt4A, true, false);
  // iter 3
  PREY(4, yaA, ybA, dt4A); SB0(); PREG(5, B2); GATE(11); COMP(B0, yaB, ybB, dt4B, true, false);
  // iter 4
  PREY(5, yaB, ybB, dt4B); SB0(); PREG(6, B0); GATE(11); COMP(B1, yaA, ybA, dt4A, true, false);
  // iter 5
  PREY(6, yaA, ybA, dt4A); SB0(); PREG(7, B1); GATE(11); COMP(B2, yaB, ybB, dt4B, true, false);
  // iter 6
  PREY(7, yaB, ybB, dt4B); SB0(); PREG8(B2);   GATE(8);  COMP(B0, yaA, ybA, dt4A, true, false);
  // iter 7
  PREY(8, yaA, ybA, dt4A); SB0();              GATE(4);  COMP(B1, yaB, ybB, dt4B, true, false);
  // iter 8 (overlap tile: only cross-tile pair counts)
                                               GATE(0);  COMP(B2, yaA, ybA, dt4A, false, false);
#undef GATE

  // ---- wave reduce; fence-free fused finalize via same-address atomic ordering
  #pragma unroll
  for (int off = 32; off > 0; off >>= 1) wacc += __shfl_down(wacc, off);
  if (lane == 0) {
    float oldv = atomicAdd(ws + b, wacc);            // returning form: ack at coherence point
    asm volatile("" :: "v"(oldv));                   // keep the return value live
    asm volatile("s_waitcnt vmcnt(0)" ::: "memory"); // ws-add globally performed before cnt-add
    int* cnt = (int*)(ws + 133632);
    int old = atomicAdd(cnt + b, 1);
    if (old == 15) {                                 // 16th (last) wave of this batch
      float v = atomicAdd(ws + b, 0.f);              // atomic read: sees all 16 adds
      out[b] = sqrtf(v * (1.0f / 3.0f));
    }
  }
}

extern "C" void kernel_launch(void* const* d_in, const int* in_sizes, int n_in,
                              void* d_out, int out_size, void* d_ws, size_t ws_size,
                              hipStream_t stream) {
  const float* times = (const float*)d_in[0];
  const float* path1 = (const float*)d_in[1];
  const float* path2 = (const float*)d_in[2];
  const float* Amat  = (const float*)d_in[3];
  float* out = (float*)d_out;
  float* ws  = (float*)d_ws;
  const int B = in_sizes[1] / (LL * CC);  // 512

  hipLaunchKernelGGL(prep_k, dim3(32), dim3(256), 0, stream, times, path2, Amat, ws);
  hipLaunchKernelGGL(l2disc_main, dim3(B * 4), dim3(256), 0, stream, path1, Amat, ws, out);
}

// Round 10
// 62.817 us; speedup vs baseline: 6.5563x; 1.0473x over previous
//
#include <hip/hip_runtime.h>
#include <hip/hip_bf16.h>

#define LL 2048
#define CC 64

typedef __bf16 bf16x8 __attribute__((ext_vector_type(8)));
typedef float f32x4 __attribute__((ext_vector_type(4)));
typedef unsigned int u32x4 __attribute__((ext_vector_type(4)));

// native RNE casts -> v_cvt_pk_bf16_f32 on gfx950
__device__ __forceinline__ bf16x8 mk8(f32x4 lo, f32x4 hi) {
  bf16x8 r;
  r[0] = (__bf16)lo[0]; r[1] = (__bf16)lo[1]; r[2] = (__bf16)lo[2]; r[3] = (__bf16)lo[3];
  r[4] = (__bf16)hi[0]; r[5] = (__bf16)hi[1]; r[6] = (__bf16)hi[2]; r[7] = (__bf16)hi[3];
  return r;
}

// pack two floats as bf16 pair: [15:0]=bf(a), [31:16]=bf(b)
__device__ __forceinline__ unsigned pk2(float a, float b) {
  __bf16 x = (__bf16)a, y = (__bf16)b;
  unsigned short ux = __builtin_bit_cast(unsigned short, x);
  unsigned short uy = __builtin_bit_cast(unsigned short, y);
  return (unsigned)ux | ((unsigned)uy << 16);
}

// unpack bf16 pair -> two exact f32 (bits<<16)
__device__ __forceinline__ f32x4 mky(unsigned ua, unsigned ub) {
  f32x4 r;
  r[0] = __builtin_bit_cast(float, ua << 16);
  r[1] = __builtin_bit_cast(float, ua & 0xffff0000u);
  r[2] = __builtin_bit_cast(float, ub << 16);
  r[3] = __builtin_bit_cast(float, ub & 0xffff0000u);
  return r;
}

// async global->LDS, 16B per lane (default cache policy)
__device__ __forceinline__ void gl16(const float* g, float* l) {
  __builtin_amdgcn_global_load_lds(
      (const __attribute__((address_space(1))) unsigned int*)g,
      (__attribute__((address_space(3))) unsigned int*)l, 16, 0, 0);
}

#define SB0() __builtin_amdgcn_sched_barrier(0)

// ws map (floats): [0,512) accum | [512,2560) dt (dt[2047]=0) |
//   [2560, 2560+65536) packed bf16 -Y2 (u32 units: tile*512 + lane*8 + t*2 + w) |
//   [133632,134144) int counters
__global__ void prep_k(const float* __restrict__ times, const float* __restrict__ path2,
                       const float* __restrict__ Amat, float* __restrict__ ws) {
  const int tid = threadIdx.x;
  const int gtid = blockIdx.x * 256 + tid;     // 32 blocks * 256 = 8192
  if (gtid < 512) {
    ws[gtid] = 0.f;
    ((int*)(ws + 133632))[gtid] = 0;
  }
  float* dt = ws + 512;
  if (gtid < 2048) dt[gtid] = (gtid < 2047) ? times[gtid + 1] - times[gtid] : 0.f;

  const int lane = tid & 63;
  const int wv = gtid >> 6;                    // 0..127 : tile index
  const int c = lane & 15, g = lane >> 4;

  bf16x8 bfr[4][2];
  #pragma unroll
  for (int t = 0; t < 4; ++t) {
    #pragma unroll
    for (int s = 0; s < 2; ++s) {
      const float* ap = Amat + (16 * t + c) * CC + 32 * s + (g << 3);
      f32x4 x0 = *(const f32x4*)ap;
      f32x4 x1 = *(const f32x4*)(ap + 4);
      bfr[t][s] = mk8(x0, x1);
    }
  }

  const int row = (wv << 4) + c;
  const float* pp2 = path2 + (size_t)row * CC + (g << 3);
  f32x4 b0 = *(const f32x4*)(pp2);      f32x4 b1 = *(const f32x4*)(pp2 + 4);
  f32x4 b2 = *(const f32x4*)(pp2 + 32); f32x4 b3 = *(const f32x4*)(pp2 + 36);
  bf16x8 af0 = mk8(b0, b1);
  bf16x8 af1 = mk8(b2, b3);

  f32x4 y[4];
  #pragma unroll
  for (int t = 0; t < 4; ++t) { f32x4 zz = {0.f,0.f,0.f,0.f}; y[t] = zz; }
  #pragma unroll
  for (int t = 0; t < 4; ++t)
    y[t] = __builtin_amdgcn_mfma_f32_16x16x32_bf16(af0, bfr[t][0], y[t], 0, 0, 0);
  #pragma unroll
  for (int t = 0; t < 4; ++t)
    y[t] = __builtin_amdgcn_mfma_f32_16x16x32_bf16(af1, bfr[t][1], y[t], 0, 0, 0);

  // store NEGATED Y2, packed bf16, per-lane contiguous 32 B
  unsigned* Y2b = (unsigned*)(ws + 2560);
  u32x4 lo = { pk2(-y[0][0], -y[0][1]), pk2(-y[0][2], -y[0][3]),
               pk2(-y[1][0], -y[1][1]), pk2(-y[1][2], -y[1][3]) };
  u32x4 hi = { pk2(-y[2][0], -y[2][1]), pk2(-y[2][2], -y[2][3]),
               pk2(-y[3][0], -y[3][1]), pk2(-y[3][2], -y[3][3]) };
  *(u32x4*)(Y2b + wv * 512 + lane * 8)     = lo;
  *(u32x4*)(Y2b + wv * 512 + lane * 8 + 4) = hi;
}

__global__ __launch_bounds__(256, 4) void l2disc_main(
    const float* __restrict__ path1, const float* __restrict__ Amat,
    float* __restrict__ ws, float* __restrict__ out)
{
  // 4 waves * 2 buffers * 1024 floats = 32 KB  -> 5 blocks/CU (LDS-limited)
  __shared__ float lds[8192];

  const int lane = threadIdx.x & 63;
  const int wave = threadIdx.x >> 6;
  const int c = lane & 15;
  const int g = lane >> 4;
  const int b = blockIdx.x >> 2;
  const int q = ((blockIdx.x & 3) << 2) | wave;   // span 0..15
  const int p0 = q << 7;

  const float* dt = ws + 512;
  const unsigned* Y2b = (const unsigned*)(ws + 2560);

  bf16x8 bfr[4][2];
  #pragma unroll
  for (int t = 0; t < 4; ++t) {
    #pragma unroll
    for (int s = 0; s < 2; ++s) {
      const float* ap = Amat + (16 * t + c) * CC + 32 * s + (g << 3);
      f32x4 x0 = *(const f32x4*)ap;
      f32x4 x1 = *(const f32x4*)(ap + 4);
      bfr[t][s] = mk8(x0, x1);
    }
  }

  // swizzled STAGE source offsets: row = 4j + (l>>4), f' = f ^ ((row&7)<<2)
  const int lr = lane >> 4, lcf = (lane & 15) << 2;
  const int soffE = lr * 64 + (lcf ^ (lr << 2));         // j even
  const int soffO = lr * 64 + (lcf ^ ((lr + 4) << 2));   // j odd
  // swizzled READ offsets within a 1024-float tile
  const int swz = (c & 7) << 2;
  const int rf0 = c * 64 + ((g << 3) ^ swz);
  const int rf1 = c * 64 + (((g << 3) | 4) ^ swz);

  float* const wl = lds + wave * 2048;
  float* const B0 = wl, * const B1 = wl + 1024;
  const float* p1base = path1 + (size_t)b * LL * CC;

  float wacc = 0.f;
  f32x4 prev = {0.f, 0.f, 0.f, 0.f};
  float dm1carry = 0.f;

  auto PREY = [&](int i, u32x4& pa, u32x4& pb, f32x4& dt4) { // 3 VMEM ops
    const int tidx = min((q << 3) + i, 127);
    const unsigned* yb = Y2b + tidx * 512 + lane * 8;
    pa = *(const u32x4*)(yb);
    pb = *(const u32x4*)(yb + 4);
    const int rd = min(p0 + (i << 4) + (g << 2), LL - 4);
    dt4 = *(const f32x4*)(dt + rd);
  };

  auto PREG = [&](int i, float* dbuf) {                     // 4 VMEM ops
    const int r0 = p0 + (i << 4);
    const float* s1 = p1base + (size_t)r0 * CC;
    gl16(s1 +       soffE, dbuf);
    gl16(s1 + 256 + soffO, dbuf + 256);
    gl16(s1 + 512 + soffE, dbuf + 512);
    gl16(s1 + 768 + soffO, dbuf + 768);
  };

  auto PREG8 = [&](float* dbuf) {                           // 1 VMEM op
    const int r0 = (q == 15) ? (LL - 16) : (p0 + 128);      // fake tile for q==15
    gl16(p1base + (size_t)r0 * CC + soffE, dbuf);           // rows r0..r0+3
  };

  auto COMP = [&](const float* u1, u32x4 pa, u32x4 pb, f32x4 dt4, bool full, bool first) {
    f32x4 a0 = *(const f32x4*)(u1 + rf0);
    f32x4 a1 = *(const f32x4*)(u1 + rf1);
    f32x4 a2 = *(const f32x4*)(u1 + rf0 + 32);
    f32x4 a3 = *(const f32x4*)(u1 + rf1 + 32);

    bf16x8 af0 = mk8(a0, a1);
    bf16x8 af1 = mk8(a2, a3);

    f32x4 y[4];
    y[0] = mky(pa[0], pa[1]);                               // acc init = -A*p2
    y[1] = mky(pa[2], pa[3]);
    y[2] = mky(pb[0], pb[1]);
    y[3] = mky(pb[2], pb[3]);
    #pragma unroll
    for (int t = 0; t < 4; ++t)
      y[t] = __builtin_amdgcn_mfma_f32_16x16x32_bf16(af0, bfr[t][0], y[t], 0, 0, 0);
    #pragma unroll
    for (int t = 0; t < 4; ++t)
      y[t] = __builtin_amdgcn_mfma_f32_16x16x32_bf16(af1, bfr[t][1], y[t], 0, 0, 0);

    const float d0 = dt4[0], d1 = dt4[1], d2 = dt4[2], d3 = dt4[3];
    const float dm1 = dm1carry;

    if (full) {
      float s0 = 0.f, s1 = 0.f, s2 = 0.f;
      #pragma unroll
      for (int t = 0; t < 4; ++t) {
        float a, bb;
        a = y[t][0]; bb = y[t][1]; s0 += a*a + a*bb + bb*bb;
        a = y[t][1]; bb = y[t][2]; s1 += a*a + a*bb + bb*bb;
        a = y[t][2]; bb = y[t][3]; s2 += a*a + a*bb + bb*bb;
      }
      wacc += d0 * s0 + d1 * s1 + d2 * s2;
      float nb0 = __shfl_down(y[0][0], 16);
      float nb1 = __shfl_down(y[1][0], 16);
      float nb2 = __shfl_down(y[2][0], 16);
      float nb3 = __shfl_down(y[3][0], 16);
      if (g < 3) {
        float a, s = 0.f;
        a = y[0][3]; s += a*a + a*nb0 + nb0*nb0;
        a = y[1][3]; s += a*a + a*nb1 + nb1*nb1;
        a = y[2][3]; s += a*a + a*nb2 + nb2*nb2;
        a = y[3][3]; s += a*a + a*nb3 + nb3*nb3;
        wacc += d3 * s;
      }
    }
    if (!first && g == 0) {
      float s = 0.f;
      #pragma unroll
      for (int t = 0; t < 4; ++t) {
        float a = prev[t], bb = y[t][0];
        s += a*a + a*bb + bb*bb;
      }
      wacc += dm1 * s;     // q==15 fake tile: dm1 = dt[2047] = 0
    }
    if (full) {
      #pragma unroll
      for (int t = 0; t < 4; ++t) prev[t] = __shfl(y[t][3], 48 + c);
    }
    dm1carry = __shfl(d3, 48);
  };

  u32x4 yaA, ybA, yaB, ybB;
  f32x4 dt4A, dt4B;

#define GATE(N) SB0(); asm volatile("s_waitcnt vmcnt(" #N ")" ::: "memory"); SB0()

  // prologue
  PREY(0, yaA, ybA, dt4A); SB0();
  PREG(0, B0);
  // iter 0
  PREY(1, yaB, ybB, dt4B); SB0(); PREG(1, B1); GATE(7); COMP(B0, yaA, ybA, dt4A, true, true);
  // iter 1
  PREY(2, yaA, ybA, dt4A); SB0(); PREG(2, B0); GATE(7); COMP(B1, yaB, ybB, dt4B, true, false);
  // iter 2
  PREY(3, yaB, ybB, dt4B); SB0(); PREG(3, B1); GATE(7); COMP(B0, yaA, ybA, dt4A, true, false);
  // iter 3
  PREY(4, yaA, ybA, dt4A); SB0(); PREG(4, B0); GATE(7); COMP(B1, yaB, ybB, dt4B, true, false);
  // iter 4
  PREY(5, yaB, ybB, dt4B); SB0(); PREG(5, B1); GATE(7); COMP(B0, yaA, ybA, dt4A, true, false);
  // iter 5
  PREY(6, yaA, ybA, dt4A); SB0(); PREG(6, B0); GATE(7); COMP(B1, yaB, ybB, dt4B, true, false);
  // iter 6
  PREY(7, yaB, ybB, dt4B); SB0(); PREG(7, B1); GATE(7); COMP(B0, yaA, ybA, dt4A, true, false);
  // iter 7
  PREY(8, yaA, ybA, dt4A); SB0(); PREG8(B0);   GATE(4); COMP(B1, yaB, ybB, dt4B, true, false);
  // iter 8 (overlap tile: only cross-tile pair counts)
                                               GATE(0); COMP(B0, yaA, ybA, dt4A, false, false);
#undef GATE

  // ---- wave reduce; fence-free fused finalize via same-address atomic ordering
  #pragma unroll
  for (int off = 32; off > 0; off >>= 1) wacc += __shfl_down(wacc, off);
  if (lane == 0) {
    float oldv = atomicAdd(ws + b, wacc);            // returning form: ack at coherence point
    asm volatile("" :: "v"(oldv));                   // keep the return value live
    asm volatile("s_waitcnt vmcnt(0)" ::: "memory"); // ws-add globally performed before cnt-add
    int* cnt = (int*)(ws + 133632);
    int old = atomicAdd(cnt + b, 1);
    if (old == 15) {                                 // 16th (last) wave of this batch
      float v = atomicAdd(ws + b, 0.f);              // atomic read: sees all 16 adds
      out[b] = sqrtf(v * (1.0f / 3.0f));
    }
  }
}

extern "C" void kernel_launch(void* const* d_in, const int* in_sizes, int n_in,
                              void* d_out, int out_size, void* d_ws, size_t ws_size,
                              hipStream_t stream) {
  const float* times = (const float*)d_in[0];
  const float* path1 = (const float*)d_in[1];
  const float* path2 = (const float*)d_in[2];
  const float* Amat  = (const float*)d_in[3];
  float* out = (float*)d_out;
  float* ws  = (float*)d_ws;
  const int B = in_sizes[1] / (LL * CC);  // 512

  hipLaunchKernelGGL(prep_k, dim3(32), dim3(256), 0, stream, times, path2, Amat, ws);
  hipLaunchKernelGGL(l2disc_main, dim3(B * 4), dim3(256), 0, stream, path1, Amat, ws, out);
}